// Round 11
// baseline (294.412 us; speedup 1.0000x reference)
//
#include <hip/hip_runtime.h>

// Problem constants (from reference)
#define NN 50000
#define NE 800000
#define IN_F 128
#define H1_F 64
#define H2_F 32
#define OUT_F 40

// bucketized CSR build
#define BSH 7                    // bucket = dst >> 7  (128 nodes per bucket)
#define NBKT 391                 // ceil(50000 / 128)
#define CAPA 4032                // per-bucket capacity (avg 2046, huge margin)
#define CHUNK 4096               // edges per binA block
#define NCH ((NE + CHUNK - 1) / CHUNK)   // 196
#define NGEMM ((NN + 63) / 64)           // 782 gemm blocks in phase1

// slab layouts: width-64 = 8 slabs x [NN][8]; width-32 = 8 slabs x [NN][4]
#define S64 ((size_t)NN * 8)     // 400000 floats per slab
#define S32 ((size_t)NN * 4)     // 200000 floats per slab

static inline int cdiv(int a, int b) { return (a + b - 1) / b; }

// pack: bkt(9) | src(16) | dloc(7)
__device__ __forceinline__ unsigned pack_e(int s, int d) {
    return ((unsigned)(d >> BSH) << 23) | ((unsigned)s << 7) | (unsigned)(d & 127);
}

// ---------------- phase 1: front GEMM (t = x @ W1 -> slab64 layout) + binA ----------------
struct GemmLDS { float Xs[64][33]; float Wsh[32][64]; };
struct BinALDS { int hist[512]; int incl[512]; int runSt[512]; int lcur[512]; int baseSh[512];
                 unsigned stage[CHUNK]; };

__global__ __launch_bounds__(256)
void phase1_k(const float* __restrict__ x, const float* __restrict__ W1,
              const int* __restrict__ src, const int* __restrict__ dst,
              unsigned* __restrict__ pairs, int* __restrict__ gCursor,
              float* __restrict__ t_out) {
    __shared__ union { GemmLDS g; BinALDS a; } lds;
    const int t = threadIdx.x;

    if (blockIdx.x < NGEMM) {
        const int rowBase = blockIdx.x * 64;
        const int tc = t % 16;
        const int tr = t / 16;
        float acc[4][4];
        #pragma unroll
        for (int i = 0; i < 4; ++i)
            #pragma unroll
            for (int j = 0; j < 4; ++j) acc[i][j] = 0.0f;

        for (int k0 = 0; k0 < IN_F; k0 += 32) {
            for (int l = t; l < 64 * 8; l += 256) {
                int r  = l / 8;
                int kk = (l % 8) * 4;
                float4 v = make_float4(0.f, 0.f, 0.f, 0.f);
                int gr = rowBase + r;
                if (gr < NN) v = *reinterpret_cast<const float4*>(x + (size_t)gr * IN_F + k0 + kk);
                lds.g.Xs[r][kk + 0] = v.x; lds.g.Xs[r][kk + 1] = v.y;
                lds.g.Xs[r][kk + 2] = v.z; lds.g.Xs[r][kk + 3] = v.w;
            }
            for (int l = t; l < 32 * 16; l += 256) {
                int kk = l / 16;
                int c  = (l % 16) * 4;
                *reinterpret_cast<float4*>(&lds.g.Wsh[kk][c]) =
                    *reinterpret_cast<const float4*>(W1 + (size_t)(k0 + kk) * H1_F + c);
            }
            __syncthreads();
            #pragma unroll
            for (int kk = 0; kk < 32; ++kk) {
                float wv[4];
                *reinterpret_cast<float4*>(wv) =
                    *reinterpret_cast<const float4*>(&lds.g.Wsh[kk][tc * 4]);
                #pragma unroll
                for (int i = 0; i < 4; ++i) {
                    float a = lds.g.Xs[tr * 4 + i][kk];
                    acc[i][0] = fmaf(a, wv[0], acc[i][0]);
                    acc[i][1] = fmaf(a, wv[1], acc[i][1]);
                    acc[i][2] = fmaf(a, wv[2], acc[i][2]);
                    acc[i][3] = fmaf(a, wv[3], acc[i][3]);
                }
            }
            __syncthreads();
        }
        // epilogue: write into slab64 layout: cols tc*4 -> slab tc/2, offset (tc&1)*4
        const int slab = tc >> 1;
        const int coff = (tc & 1) * 4;
        #pragma unroll
        for (int i = 0; i < 4; ++i) {
            int gr = rowBase + tr * 4 + i;
            if (gr < NN) {
                float4 v;
                v.x = acc[i][0]; v.y = acc[i][1]; v.z = acc[i][2]; v.w = acc[i][3];
                *reinterpret_cast<float4*>(t_out + (size_t)slab * S64 + (size_t)gr * 8 + coff) = v;
            }
        }
    } else {
        const int e0 = (blockIdx.x - NGEMM) * CHUNK;
        const int n = min(CHUNK, NE - e0);
        lds.a.hist[t] = 0; lds.a.hist[t + 256] = 0;
        __syncthreads();
        for (int i = t; i < n; i += 256) {
            int d = dst[e0 + i];
            atomicAdd(&lds.a.hist[d >> BSH], 1);
        }
        __syncthreads();
        lds.a.incl[t] = lds.a.hist[t]; lds.a.incl[t + 256] = lds.a.hist[t + 256];
        __syncthreads();
        for (int off = 1; off < 512; off <<= 1) {
            int v0 = (t >= off) ? lds.a.incl[t - off] : 0;
            int v1 = (t + 256 >= off) ? lds.a.incl[t + 256 - off] : 0;
            __syncthreads();
            lds.a.incl[t] += v0; lds.a.incl[t + 256] += v1;
            __syncthreads();
        }
        lds.a.runSt[t]       = lds.a.incl[t] - lds.a.hist[t];
        lds.a.runSt[t + 256] = lds.a.incl[t + 256] - lds.a.hist[t + 256];
        lds.a.lcur[t]        = lds.a.runSt[t];
        lds.a.lcur[t + 256]  = lds.a.runSt[t + 256];
        __syncthreads();
        for (int i = t; i < n; i += 256) {
            int s = src[e0 + i], d = dst[e0 + i];
            int b = d >> BSH;
            int p = atomicAdd(&lds.a.lcur[b], 1);
            lds.a.stage[p] = pack_e(s, d);
        }
        for (int b = t; b < NBKT; b += 256) {
            int c = lds.a.hist[b];
            lds.a.baseSh[b] = c ? atomicAdd(&gCursor[b], c) : 0;
        }
        __syncthreads();
        for (int i = t; i < n; i += 256) {
            unsigned p = lds.a.stage[i];
            int b = (int)(p >> 23);
            int gp = lds.a.baseSh[b] + (i - lds.a.runSt[b]);
            if (gp < CAPA) pairs[(size_t)b * CAPA + gp] = p;
        }
    }
}

// ---------------- binB: histogram -> dinv + rowptr + csr16 scatter + t-slab scale ----------
__global__ __launch_bounds__(256)
void binB_k(const unsigned* __restrict__ pairs, const int* __restrict__ gCursor,
            int2* __restrict__ rowptr, float* __restrict__ dinv,
            unsigned short* __restrict__ csr16, float* __restrict__ t_rows) {
    const int b = blockIdx.x;
    const int nodeBase = b << BSH;
    const int nNodes = min(128, NN - nodeBase);
    int count = min(gCursor[b], CAPA);
    const int seg = b * CAPA;
    __shared__ int hist[128], incl[128], lcur[128];
    __shared__ float dsh[128];
    const int t = threadIdx.x;
    if (t < 128) hist[t] = 0;
    __syncthreads();
    const unsigned* bp = pairs + (size_t)b * CAPA;
    for (int i = t; i < count; i += 256) {
        atomicAdd(&hist[bp[i] & 127], 1);
    }
    __syncthreads();
    if (t < 128) incl[t] = hist[t];
    __syncthreads();
    for (int off = 1; off < 128; off <<= 1) {
        int v = (t < 128 && t >= off) ? incl[t - off] : 0;
        __syncthreads();
        if (t < 128) incl[t] += v;
        __syncthreads();
    }
    if (t < nNodes) {
        int e = seg + incl[t];
        rowptr[nodeBase + t] = make_int2(e - hist[t], e);
        float dv = rsqrtf((float)hist[t] + 1.0f);   // +1 self-loop
        dinv[nodeBase + t] = dv;
        dsh[t] = dv;
        lcur[t] = e - hist[t];
    }
    __syncthreads();
    for (int i = t; i < count; i += 256) {
        unsigned p = bp[i];
        int pos = atomicAdd(&lcur[p & 127], 1);
        csr16[pos] = (unsigned short)((p >> 7) & 0xFFFFu);
    }
    // scale this bucket's t rows (slab64 layout) by dinv
    for (int s = 0; s < 8; ++s) {
        for (int i = t; i < nNodes * 2; i += 256) {
            int n = i >> 1, c4 = (i & 1) * 4;
            float4* p = reinterpret_cast<float4*>(
                t_rows + (size_t)s * S64 + (size_t)(nodeBase + n) * 8 + c4);
            float4 v = *p;
            float sc = dsh[n];
            v.x *= sc; v.y *= sc; v.z *= sc; v.w *= sc;
            *p = v;
        }
    }
}

// ---------------- slabbed width-64 pull: 2 lanes/node, slab = blockIdx & 7 ----------------
// EPI=false: out = dinv^2 * (self + sum)      (hop 1, hop 3-equivalent)
// EPI=true:  out = relu(dinv * (self+sum) + bias[slab*8+col])   (hop 2)
template<bool EPI>
__global__ __launch_bounds__(256)
void pull64s_k(const float* __restrict__ in, const unsigned short* __restrict__ csr,
               const int2* __restrict__ rowptr, const float* __restrict__ dinv,
               const float* __restrict__ bias, float* __restrict__ out) {
    const int t = threadIdx.x;
    const int slab = blockIdx.x & 7;
    const int node = ((blockIdx.x >> 3) << 7) + (t >> 1);   // 128 nodes/block
    const int col  = (t & 1) * 4;
    if (node >= NN) return;
    const float* sin = in + (size_t)slab * S64;
    const int2 rp = rowptr[node];
    float4 a0 = *reinterpret_cast<const float4*>(sin + (size_t)node * 8 + col);  // self
    float4 a1 = make_float4(0.f, 0.f, 0.f, 0.f);
    float4 a2 = make_float4(0.f, 0.f, 0.f, 0.f);
    float4 a3 = make_float4(0.f, 0.f, 0.f, 0.f);
    int k = rp.x;
    for (; k + 3 < rp.y; k += 4) {
        int s0 = csr[k], s1 = csr[k + 1], s2 = csr[k + 2], s3 = csr[k + 3];
        float4 v0 = *reinterpret_cast<const float4*>(sin + (size_t)s0 * 8 + col);
        float4 v1 = *reinterpret_cast<const float4*>(sin + (size_t)s1 * 8 + col);
        float4 v2 = *reinterpret_cast<const float4*>(sin + (size_t)s2 * 8 + col);
        float4 v3 = *reinterpret_cast<const float4*>(sin + (size_t)s3 * 8 + col);
        a0.x += v0.x; a0.y += v0.y; a0.z += v0.z; a0.w += v0.w;
        a1.x += v1.x; a1.y += v1.y; a1.z += v1.z; a1.w += v1.w;
        a2.x += v2.x; a2.y += v2.y; a2.z += v2.z; a2.w += v2.w;
        a3.x += v3.x; a3.y += v3.y; a3.z += v3.z; a3.w += v3.w;
    }
    for (; k < rp.y; ++k) {
        int s0 = csr[k];
        float4 v0 = *reinterpret_cast<const float4*>(sin + (size_t)s0 * 8 + col);
        a0.x += v0.x; a0.y += v0.y; a0.z += v0.z; a0.w += v0.w;
    }
    float dd = dinv[node];
    float4 r;
    if (EPI) {
        const float4 bv = *reinterpret_cast<const float4*>(bias + slab * 8 + col);
        r.x = fmaxf((a0.x + a1.x + a2.x + a3.x) * dd + bv.x, 0.f);
        r.y = fmaxf((a0.y + a1.y + a2.y + a3.y) * dd + bv.y, 0.f);
        r.z = fmaxf((a0.z + a1.z + a2.z + a3.z) * dd + bv.z, 0.f);
        r.w = fmaxf((a0.w + a1.w + a2.w + a3.w) * dd + bv.w, 0.f);
    } else {
        float sc = dd * dd;
        r.x = (a0.x + a1.x + a2.x + a3.x) * sc;
        r.y = (a0.y + a1.y + a2.y + a3.y) * sc;
        r.z = (a0.z + a1.z + a2.z + a3.z) * sc;
        r.w = (a0.w + a1.w + a2.w + a3.w) * sc;
    }
    *reinterpret_cast<float4*>(out + (size_t)slab * S64 + (size_t)node * 8 + col) = r;
}

// ---------------- slabbed width-32 pull: 1 lane/node, slab = blockIdx & 7 ----------------
template<bool EPI>
__global__ __launch_bounds__(256)
void pull32s_k(const float* __restrict__ in, const unsigned short* __restrict__ csr,
               const int2* __restrict__ rowptr, const float* __restrict__ dinv,
               const float* __restrict__ bias, float* __restrict__ out) {
    const int t = threadIdx.x;
    const int slab = blockIdx.x & 7;
    const int node = ((blockIdx.x >> 3) << 8) + t;          // 256 nodes/block
    if (node >= NN) return;
    const float* sin = in + (size_t)slab * S32;
    const int2 rp = rowptr[node];
    float4 a0 = *reinterpret_cast<const float4*>(sin + (size_t)node * 4);  // self
    float4 a1 = make_float4(0.f, 0.f, 0.f, 0.f);
    float4 a2 = make_float4(0.f, 0.f, 0.f, 0.f);
    float4 a3 = make_float4(0.f, 0.f, 0.f, 0.f);
    int k = rp.x;
    for (; k + 3 < rp.y; k += 4) {
        int s0 = csr[k], s1 = csr[k + 1], s2 = csr[k + 2], s3 = csr[k + 3];
        float4 v0 = *reinterpret_cast<const float4*>(sin + (size_t)s0 * 4);
        float4 v1 = *reinterpret_cast<const float4*>(sin + (size_t)s1 * 4);
        float4 v2 = *reinterpret_cast<const float4*>(sin + (size_t)s2 * 4);
        float4 v3 = *reinterpret_cast<const float4*>(sin + (size_t)s3 * 4);
        a0.x += v0.x; a0.y += v0.y; a0.z += v0.z; a0.w += v0.w;
        a1.x += v1.x; a1.y += v1.y; a1.z += v1.z; a1.w += v1.w;
        a2.x += v2.x; a2.y += v2.y; a2.z += v2.z; a2.w += v2.w;
        a3.x += v3.x; a3.y += v3.y; a3.z += v3.z; a3.w += v3.w;
    }
    for (; k < rp.y; ++k) {
        int s0 = csr[k];
        float4 v0 = *reinterpret_cast<const float4*>(sin + (size_t)s0 * 4);
        a0.x += v0.x; a0.y += v0.y; a0.z += v0.z; a0.w += v0.w;
    }
    float dd = dinv[node];
    float4 r;
    if (EPI) {
        const float4 bv = *reinterpret_cast<const float4*>(bias + slab * 4);
        r.x = fmaxf((a0.x + a1.x + a2.x + a3.x) * dd + bv.x, 0.f);
        r.y = fmaxf((a0.y + a1.y + a2.y + a3.y) * dd + bv.y, 0.f);
        r.z = fmaxf((a0.z + a1.z + a2.z + a3.z) * dd + bv.z, 0.f);
        r.w = fmaxf((a0.w + a1.w + a2.w + a3.w) * dd + bv.w, 0.f);
    } else {
        float sc = dd * dd;
        r.x = (a0.x + a1.x + a2.x + a3.x) * sc;
        r.y = (a0.y + a1.y + a2.y + a3.y) * sc;
        r.z = (a0.z + a1.z + a2.z + a3.z) * sc;
        r.w = (a0.w + a1.w + a2.w + a3.w) * sc;
    }
    *reinterpret_cast<float4*>(out + (size_t)slab * S32 + (size_t)node * 4) = r;
}

// ---------------- GEMM2: t2 = dinv * (h @ W2), h from slab64, t2 to slab32 ----------------
__global__ __launch_bounds__(256)
void gemm2_k(const float* __restrict__ h, const float* __restrict__ W2,
             const float* __restrict__ dinv, float* __restrict__ t2) {
    __shared__ float hs[64][68];
    __shared__ float W2s[64][32];
    const int t = threadIdx.x;
    const int n0 = blockIdx.x * 64;
    for (int i = t; i < 64 * 32 / 4; i += 256)
        reinterpret_cast<float4*>(&W2s[0][0])[i] = reinterpret_cast<const float4*>(W2)[i];
    for (int idx = t; idx < 1024; idx += 256) {   // 8 slabs x 64 nodes x 2 float4
        int s = idx >> 7;
        int r = (idx >> 1) & 63;
        int c2 = (idx & 1) * 4;
        int node = n0 + r;
        float4 v = make_float4(0.f, 0.f, 0.f, 0.f);
        if (node < NN) v = *reinterpret_cast<const float4*>(h + (size_t)s * S64 + (size_t)node * 8 + c2);
        *reinterpret_cast<float4*>(&hs[r][s * 8 + c2]) = v;
    }
    __syncthreads();
    const int r = t >> 2;
    const int c0 = (t & 3) * 8;
    float acc[8];
    #pragma unroll
    for (int j = 0; j < 8; ++j) acc[j] = 0.f;
    #pragma unroll 4
    for (int k = 0; k < 64; k += 4) {
        float4 av = *reinterpret_cast<const float4*>(&hs[r][k]);
        #pragma unroll
        for (int kk = 0; kk < 4; ++kk) {
            float a = (&av.x)[kk];
            float4 w0 = *reinterpret_cast<const float4*>(&W2s[k + kk][c0]);
            float4 w1 = *reinterpret_cast<const float4*>(&W2s[k + kk][c0 + 4]);
            acc[0] = fmaf(a, w0.x, acc[0]); acc[1] = fmaf(a, w0.y, acc[1]);
            acc[2] = fmaf(a, w0.z, acc[2]); acc[3] = fmaf(a, w0.w, acc[3]);
            acc[4] = fmaf(a, w1.x, acc[4]); acc[5] = fmaf(a, w1.y, acc[5]);
            acc[6] = fmaf(a, w1.z, acc[6]); acc[7] = fmaf(a, w1.w, acc[7]);
        }
    }
    const int node = n0 + r;
    if (node < NN) {
        const float sc = dinv[node];
        float4 o0, o1;
        o0.x = acc[0] * sc; o0.y = acc[1] * sc; o0.z = acc[2] * sc; o0.w = acc[3] * sc;
        o1.x = acc[4] * sc; o1.y = acc[5] * sc; o1.z = acc[6] * sc; o1.w = acc[7] * sc;
        const int s0 = c0 >> 2;     // slab of cols c0..c0+3
        *reinterpret_cast<float4*>(t2 + (size_t)s0 * S32 + (size_t)node * 4)       = o0;
        *reinterpret_cast<float4*>(t2 + (size_t)(s0 + 1) * S32 + (size_t)node * 4) = o1;
    }
}

// ---------------- GEMMF: emb (node-major, d_out) from e-slabs; logits = emb @ Wf + bf ------
__global__ __launch_bounds__(256)
void gemmF_k(const float* __restrict__ e, const float* __restrict__ Wf,
             const float* __restrict__ bf, float* __restrict__ embOut,
             float* __restrict__ logits) {
    __shared__ float es[64][36];
    __shared__ float Wfs[32][40];
    __shared__ float bfs[40];
    const int t = threadIdx.x;
    const int n0 = blockIdx.x * 64;
    for (int i = t; i < 32 * 40 / 4; i += 256)
        reinterpret_cast<float4*>(&Wfs[0][0])[i] = reinterpret_cast<const float4*>(Wf)[i];
    if (t < 40) bfs[t] = bf[t];
    for (int idx = t; idx < 512; idx += 256) {    // 8 slabs x 64 nodes x 1 float4
        int s = idx >> 6;
        int r = idx & 63;
        int node = n0 + r;
        float4 v = make_float4(0.f, 0.f, 0.f, 0.f);
        if (node < NN) v = *reinterpret_cast<const float4*>(e + (size_t)s * S32 + (size_t)node * 4);
        *reinterpret_cast<float4*>(&es[r][s * 4]) = v;
    }
    __syncthreads();
    // emb write: node-major coalesced
    for (int idx = t; idx < 512; idx += 256) {
        int r = idx >> 3;
        int c4 = (idx & 7) * 4;
        int node = n0 + r;
        if (node < NN)
            *reinterpret_cast<float4*>(embOut + (size_t)node * 32 + c4) =
                *reinterpret_cast<const float4*>(&es[r][c4]);
    }
    // logits
    const int r = t >> 2;
    const int c0 = (t & 3) * 10;
    float acc[10];
    #pragma unroll
    for (int j = 0; j < 10; ++j) acc[j] = bfs[c0 + j];
    #pragma unroll 4
    for (int k = 0; k < 32; k += 4) {
        float4 av = *reinterpret_cast<const float4*>(&es[r][k]);
        #pragma unroll
        for (int kk = 0; kk < 4; ++kk) {
            float a = (&av.x)[kk];
            #pragma unroll
            for (int j = 0; j < 10; ++j)
                acc[j] = fmaf(a, Wfs[k + kk][c0 + j], acc[j]);
        }
    }
    const int node = n0 + r;
    if (node < NN) {
        float* lp = logits + (size_t)node * 40 + c0;
        #pragma unroll
        for (int j = 0; j < 10; ++j) lp[j] = acc[j];
    }
}

extern "C" void kernel_launch(void* const* d_in, const int* in_sizes, int n_in,
                              void* d_out, int out_size, void* d_ws, size_t ws_size,
                              hipStream_t stream) {
    const float* x  = (const float*)d_in[0];
    const int*   ei = (const int*)d_in[1];
    const float* W1 = (const float*)d_in[2];
    const float* b1 = (const float*)d_in[3];
    const float* W2 = (const float*)d_in[4];
    const float* b2 = (const float*)d_in[5];
    const float* Wf = (const float*)d_in[6];
    const float* bf = (const float*)d_in[7];

    float* out    = (float*)d_out;
    float* embOut = out;                       // [N, 32]
    float* logits = out + (size_t)NN * H2_F;   // [N, 40]

    const int* src = ei;        // edge_index[0]
    const int* dst = ei + NE;   // edge_index[1]

    // workspace layout
    float* ws = (float*)d_ws;
    float*          dinv   = ws;                                 // NN f32
    int2*           rowptr = (int2*)(ws + NN);                   // NN int2
    unsigned short* csr16  = (unsigned short*)(rowptr + NN);     // NBKT*CAPA u16 (3.15MB)
    int*            gCursor= (int*)((char*)csr16 + (size_t)NBKT * CAPA * 2);
    float*          bufA   = (float*)(gCursor + 512);            // 8*S64 f32 (12.8MB)
    float*          bufB   = bufA + 8 * S64;                     // 8*S64 f32
    unsigned*       pairs  = (unsigned*)bufB;                    // 6.3MB alias (dead before pull1 writes bufB)

    // ---- CSR build + front GEMM (t = dinv*(x@W1) in slab64; scale applied in binB) ----
    hipMemsetAsync(gCursor, 0, NBKT * sizeof(int), stream);
    phase1_k<<<NGEMM + NCH, 256, 0, stream>>>(x, W1, src, dst, pairs, gCursor, bufA);
    binB_k<<<NBKT, 256, 0, stream>>>(pairs, gCursor, rowptr, dinv, csr16, bufA);

    // ---- layer 1: v = dinv^2*(S t); h = relu(dinv*(S v) + b1); t2 = dinv*(h@W2) ----
    pull64s_k<false><<<8 * cdiv(NN, 128), 256, 0, stream>>>(bufA, csr16, rowptr, dinv, nullptr, bufB);
    pull64s_k<true> <<<8 * cdiv(NN, 128), 256, 0, stream>>>(bufB, csr16, rowptr, dinv, b1, bufA);
    gemm2_k<<<cdiv(NN, 64), 256, 0, stream>>>(bufA, W2, dinv, bufB);

    // ---- layer 2: u = dinv^2*(S t2); e = relu(dinv*(S u) + b2); out = e, e@Wf+bf ----
    pull32s_k<false><<<8 * cdiv(NN, 256), 256, 0, stream>>>(bufB, csr16, rowptr, dinv, nullptr, bufA);
    pull32s_k<true> <<<8 * cdiv(NN, 256), 256, 0, stream>>>(bufA, csr16, rowptr, dinv, b2, bufB);
    gemmF_k<<<cdiv(NN, 64), 256, 0, stream>>>(bufB, Wf, bf, embOut, logits);
}

// Round 12
// 231.772 us; speedup vs baseline: 1.2703x; 1.2703x over previous
//
#include <hip/hip_runtime.h>

// Problem constants (from reference)
#define NN 50000
#define NE 800000
#define IN_F 128
#define H1_F 64
#define H2_F 32
#define OUT_F 40

// bucketized CSR build
#define BSH 7                    // bucket = dst >> 7  (128 nodes per bucket)
#define NBKT 391                 // ceil(50000 / 128)
#define CAPA 4032                // per-bucket capacity (avg 2046; 12.6MB total, aliases bufB)
#define CHUNK 4096               // edges per binA block
#define NCH ((NE + CHUNK - 1) / CHUNK)   // 196

static inline int cdiv(int a, int b) { return (a + b - 1) / b; }

// ---------------- CSR build: two-phase bucketized counting sort (round-7 verbatim) ----------
__global__ void initcur_k(int* __restrict__ gCursor) {
    int b = blockIdx.x * 256 + threadIdx.x;
    if (b < NBKT) gCursor[b] = b * CAPA;
}

__global__ __launch_bounds__(256)
void binA_k(const int* __restrict__ src, const int* __restrict__ dst,
            uint2* __restrict__ pairs, int* __restrict__ gCursor) {
    __shared__ int hist[512], incl[512], runSt[512], lcur[512], baseSh[512];
    __shared__ uint2 stage[CHUNK];
    const int t = threadIdx.x;
    const int e0 = blockIdx.x * CHUNK;
    const int n = min(CHUNK, NE - e0);

    hist[t] = 0; hist[t + 256] = 0;
    __syncthreads();
    for (int i = t; i < n; i += 256) {
        int d = dst[e0 + i];
        atomicAdd(&hist[d >> BSH], 1);
    }
    __syncthreads();
    incl[t] = hist[t]; incl[t + 256] = hist[t + 256];
    __syncthreads();
    for (int off = 1; off < 512; off <<= 1) {
        int v0 = (t >= off) ? incl[t - off] : 0;
        int v1 = (t + 256 >= off) ? incl[t + 256 - off] : 0;
        __syncthreads();
        incl[t] += v0; incl[t + 256] += v1;
        __syncthreads();
    }
    runSt[t] = incl[t] - hist[t];   runSt[t + 256] = incl[t + 256] - hist[t + 256];
    lcur[t]  = runSt[t];            lcur[t + 256]  = runSt[t + 256];
    __syncthreads();
    for (int i = t; i < n; i += 256) {
        int s = src[e0 + i], d = dst[e0 + i];
        int b = d >> BSH;
        int p = atomicAdd(&lcur[b], 1);
        stage[p] = make_uint2((unsigned)s, (unsigned)d);
    }
    for (int b = t; b < NBKT; b += 256) {
        int c = hist[b];
        baseSh[b] = c ? atomicAdd(&gCursor[b], c) : 0;
    }
    __syncthreads();
    for (int i = t; i < n; i += 256) {
        uint2 p = stage[i];
        int b = (int)(p.y >> BSH);
        int gp = baseSh[b] + (i - runSt[b]);
        if (gp < (b + 1) * CAPA) pairs[gp] = p;
    }
}

__global__ __launch_bounds__(512)
void segscan_k(const int* __restrict__ gCursor, int* __restrict__ segBase) {
    __shared__ int sh[512], orig[512];
    int t = threadIdx.x;
    int c = 0;
    if (t < NBKT) {
        c = gCursor[t] - t * CAPA;
        c = max(0, min(c, CAPA));
    }
    sh[t] = c; orig[t] = c;
    __syncthreads();
    for (int off = 1; off < 512; off <<= 1) {
        int v = (t >= off) ? sh[t - off] : 0;
        __syncthreads();
        sh[t] += v;
        __syncthreads();
    }
    if (t < NBKT) segBase[t] = sh[t] - orig[t];
}

__global__ __launch_bounds__(256)
void binB_k(const uint2* __restrict__ pairs, const int* __restrict__ gCursor,
            const int* __restrict__ segBase, int* __restrict__ cursor,
            float* __restrict__ dinv, int* __restrict__ csr) {
    const int b = blockIdx.x;
    const int nodeBase = b << BSH;
    const int nNodes = min(128, NN - nodeBase);
    int count = gCursor[b] - b * CAPA;
    count = max(0, min(count, CAPA));
    const int seg = segBase[b];
    __shared__ int hist[128], incl[128], lcur[128];
    const int t = threadIdx.x;
    if (t < 128) hist[t] = 0;
    __syncthreads();
    const uint2* bp = pairs + (size_t)b * CAPA;
    for (int i = t; i < count; i += 256) {
        int d = (int)bp[i].y - nodeBase;
        atomicAdd(&hist[d], 1);
    }
    __syncthreads();
    if (t < 128) incl[t] = hist[t];
    __syncthreads();
    for (int off = 1; off < 128; off <<= 1) {
        int v = (t < 128 && t >= off) ? incl[t - off] : 0;
        __syncthreads();
        if (t < 128) incl[t] += v;
        __syncthreads();
    }
    if (t < nNodes) {
        cursor[nodeBase + t] = seg + incl[t];
        dinv[nodeBase + t]   = rsqrtf((float)hist[t] + 1.0f);
        lcur[t] = seg + incl[t] - hist[t];
    }
    __syncthreads();
    for (int i = t; i < count; i += 256) {
        uint2 p = bp[i];
        int d = (int)p.y - nodeBase;
        int pos = atomicAdd(&lcur[d], 1);
        csr[pos] = (int)p.x;
    }
}

// ---------------- register-tiled GEMM (layer-1 front GEMM only, round-7 verbatim) ----------
template<int K, int F, int CT, int RPT, int BLOCK, bool BIAS, bool SCALE>
__global__ __launch_bounds__(BLOCK)
void gemm_tile_k(const float* __restrict__ X, const float* __restrict__ W,
                 const float* __restrict__ b, const float* __restrict__ dinv,
                 float* __restrict__ Y) {
    constexpr int RT = BLOCK / CT;
    constexpr int TR = RT * RPT;
    constexpr int KT = 32;
    constexpr int KPAD = KT + 1;
    __shared__ float Xs[TR][KPAD];
    __shared__ float Wsh[KT][F];
    const int rowBase = blockIdx.x * TR;
    const int tc = threadIdx.x % CT;
    const int tr = threadIdx.x / CT;

    float acc[RPT][4];
    #pragma unroll
    for (int i = 0; i < RPT; ++i)
        #pragma unroll
        for (int j = 0; j < 4; ++j) acc[i][j] = 0.0f;

    for (int k0 = 0; k0 < K; k0 += KT) {
        constexpr int XL4 = TR * KT / 4;
        for (int l = threadIdx.x; l < XL4; l += BLOCK) {
            int r  = l / (KT / 4);
            int kk = (l % (KT / 4)) * 4;
            float4 v = make_float4(0.f, 0.f, 0.f, 0.f);
            int gr = rowBase + r;
            if (gr < NN) v = *reinterpret_cast<const float4*>(X + (size_t)gr * K + k0 + kk);
            Xs[r][kk + 0] = v.x; Xs[r][kk + 1] = v.y;
            Xs[r][kk + 2] = v.z; Xs[r][kk + 3] = v.w;
        }
        constexpr int WL4 = KT * F / 4;
        for (int l = threadIdx.x; l < WL4; l += BLOCK) {
            int kk = l / (F / 4);
            int c  = (l % (F / 4)) * 4;
            *reinterpret_cast<float4*>(&Wsh[kk][c]) =
                *reinterpret_cast<const float4*>(W + (size_t)(k0 + kk) * F + c);
        }
        __syncthreads();
        #pragma unroll
        for (int kk = 0; kk < KT; ++kk) {
            float wv[4];
            *reinterpret_cast<float4*>(wv) = *reinterpret_cast<const float4*>(&Wsh[kk][tc * 4]);
            #pragma unroll
            for (int i = 0; i < RPT; ++i) {
                float a = Xs[tr * RPT + i][kk];
                acc[i][0] = fmaf(a, wv[0], acc[i][0]);
                acc[i][1] = fmaf(a, wv[1], acc[i][1]);
                acc[i][2] = fmaf(a, wv[2], acc[i][2]);
                acc[i][3] = fmaf(a, wv[3], acc[i][3]);
            }
        }
        __syncthreads();
    }
    #pragma unroll
    for (int i = 0; i < RPT; ++i) {
        int gr = rowBase + tr * RPT + i;
        if (gr < NN) {
            float sc = SCALE ? dinv[gr] : 1.0f;
            float4 v;
            v.x = acc[i][0]; v.y = acc[i][1]; v.z = acc[i][2]; v.w = acc[i][3];
            if (BIAS) {
                v.x += b[tc * 4 + 0]; v.y += b[tc * 4 + 1];
                v.z += b[tc * 4 + 2]; v.w += b[tc * 4 + 3];
            }
            v.x *= sc; v.y *= sc; v.z *= sc; v.w *= sc;
            *reinterpret_cast<float4*>(Y + (size_t)gr * F + tc * 4) = v;
        }
    }
}

// ---------------- pull: out[d] = dinv_d^2 * (in[d] + sum in[s]), 4-deep ILP (round-7) ------
template<int F>
__global__ __launch_bounds__(256)
void pull4_k(const float* __restrict__ in, const int* __restrict__ csr,
             const int* __restrict__ cursor, const float* __restrict__ dinv,
             float* __restrict__ out) {
    constexpr int LPN = F / 4;
    constexpr int NPB = 256 / LPN;
    const int t = threadIdx.x;
    const int node = blockIdx.x * NPB + t / LPN;
    const int col  = (t % LPN) * 4;
    if (node >= NN) return;
    const int beg = (node == 0) ? 0 : cursor[node - 1];
    const int end = cursor[node];
    float4 a0 = *reinterpret_cast<const float4*>(in + (size_t)node * F + col);  // self
    float4 a1 = make_float4(0.f, 0.f, 0.f, 0.f);
    float4 a2 = make_float4(0.f, 0.f, 0.f, 0.f);
    float4 a3 = make_float4(0.f, 0.f, 0.f, 0.f);
    int k = beg;
    for (; k + 3 < end; k += 4) {
        int s0 = csr[k], s1 = csr[k + 1], s2 = csr[k + 2], s3 = csr[k + 3];
        float4 v0 = *reinterpret_cast<const float4*>(in + (size_t)s0 * F + col);
        float4 v1 = *reinterpret_cast<const float4*>(in + (size_t)s1 * F + col);
        float4 v2 = *reinterpret_cast<const float4*>(in + (size_t)s2 * F + col);
        float4 v3 = *reinterpret_cast<const float4*>(in + (size_t)s3 * F + col);
        a0.x += v0.x; a0.y += v0.y; a0.z += v0.z; a0.w += v0.w;
        a1.x += v1.x; a1.y += v1.y; a1.z += v1.z; a1.w += v1.w;
        a2.x += v2.x; a2.y += v2.y; a2.z += v2.z; a2.w += v2.w;
        a3.x += v3.x; a3.y += v3.y; a3.z += v3.z; a3.w += v3.w;
    }
    for (; k < end; ++k) {
        int s0 = csr[k];
        float4 v0 = *reinterpret_cast<const float4*>(in + (size_t)s0 * F + col);
        a0.x += v0.x; a0.y += v0.y; a0.z += v0.z; a0.w += v0.w;
    }
    float sc = dinv[node]; sc *= sc;
    float4 r;
    r.x = (a0.x + a1.x + a2.x + a3.x) * sc;
    r.y = (a0.y + a1.y + a2.y + a3.y) * sc;
    r.z = (a0.z + a1.z + a2.z + a3.z) * sc;
    r.w = (a0.w + a1.w + a2.w + a3.w) * sc;
    *reinterpret_cast<float4*>(out + (size_t)node * F + col) = r;
}

// ---------------- fused: hop-2 pull (+relu) + GEMM W2 + dinv scale  (32 nodes/block) --------
// h = relu(dinv_d*(v[d]+sum v[s]) + b1);  t2[d] = dinv_d * (h @ W2)   [64 -> 32]
__global__ __launch_bounds__(256)
void pullgemm2_k(const float* __restrict__ in, const int* __restrict__ csr,
                 const int* __restrict__ cursor, const float* __restrict__ dinv,
                 const float* __restrict__ b1, const float* __restrict__ W2,
                 float* __restrict__ outT) {
    __shared__ float hs[32][68];
    __shared__ float W2s[64][32];
    const int t = threadIdx.x;
    for (int i = t; i < 64 * 32 / 4; i += 256)
        reinterpret_cast<float4*>(&W2s[0][0])[i] = reinterpret_cast<const float4*>(W2)[i];
    const int nodeBase = blockIdx.x * 32;
    #pragma unroll
    for (int pass = 0; pass < 2; ++pass) {
        const int nb = pass * 16 + t / 16;
        const int node = nodeBase + nb;
        const int col = (t % 16) * 4;
        float4 r = make_float4(0.f, 0.f, 0.f, 0.f);
        if (node < NN) {
            const int beg = (node == 0) ? 0 : cursor[node - 1];
            const int end = cursor[node];
            float4 a0 = *reinterpret_cast<const float4*>(in + (size_t)node * 64 + col);
            float4 a1 = make_float4(0.f, 0.f, 0.f, 0.f);
            float4 a2 = make_float4(0.f, 0.f, 0.f, 0.f);
            float4 a3 = make_float4(0.f, 0.f, 0.f, 0.f);
            int k = beg;
            for (; k + 3 < end; k += 4) {
                int s0 = csr[k], s1 = csr[k + 1], s2 = csr[k + 2], s3 = csr[k + 3];
                float4 v0 = *reinterpret_cast<const float4*>(in + (size_t)s0 * 64 + col);
                float4 v1 = *reinterpret_cast<const float4*>(in + (size_t)s1 * 64 + col);
                float4 v2 = *reinterpret_cast<const float4*>(in + (size_t)s2 * 64 + col);
                float4 v3 = *reinterpret_cast<const float4*>(in + (size_t)s3 * 64 + col);
                a0.x += v0.x; a0.y += v0.y; a0.z += v0.z; a0.w += v0.w;
                a1.x += v1.x; a1.y += v1.y; a1.z += v1.z; a1.w += v1.w;
                a2.x += v2.x; a2.y += v2.y; a2.z += v2.z; a2.w += v2.w;
                a3.x += v3.x; a3.y += v3.y; a3.z += v3.z; a3.w += v3.w;
            }
            for (; k < end; ++k) {
                int s0 = csr[k];
                float4 v0 = *reinterpret_cast<const float4*>(in + (size_t)s0 * 64 + col);
                a0.x += v0.x; a0.y += v0.y; a0.z += v0.z; a0.w += v0.w;
            }
            const float sc = dinv[node];
            const float4 bv = *reinterpret_cast<const float4*>(b1 + col);
            r.x = fmaxf((a0.x + a1.x + a2.x + a3.x) * sc + bv.x, 0.f);
            r.y = fmaxf((a0.y + a1.y + a2.y + a3.y) * sc + bv.y, 0.f);
            r.z = fmaxf((a0.z + a1.z + a2.z + a3.z) * sc + bv.z, 0.f);
            r.w = fmaxf((a0.w + a1.w + a2.w + a3.w) * sc + bv.w, 0.f);
        }
        *reinterpret_cast<float4*>(&hs[nb][col]) = r;
    }
    __syncthreads();
    // GEMM: 32 rows x 32 cols, thread owns (row, 4 cols)
    const int r = t / 8;
    const int c0 = (t % 8) * 4;
    float acc[4] = {0.f, 0.f, 0.f, 0.f};
    #pragma unroll 4
    for (int k = 0; k < 64; k += 4) {
        float4 av = *reinterpret_cast<const float4*>(&hs[r][k]);
        #pragma unroll
        for (int kk = 0; kk < 4; ++kk) {
            float a = (&av.x)[kk];
            float4 w = *reinterpret_cast<const float4*>(&W2s[k + kk][c0]);
            acc[0] = fmaf(a, w.x, acc[0]); acc[1] = fmaf(a, w.y, acc[1]);
            acc[2] = fmaf(a, w.z, acc[2]); acc[3] = fmaf(a, w.w, acc[3]);
        }
    }
    const int node = nodeBase + r;
    if (node < NN) {
        const float sc = dinv[node];
        float4 o;
        o.x = acc[0] * sc; o.y = acc[1] * sc; o.z = acc[2] * sc; o.w = acc[3] * sc;
        *reinterpret_cast<float4*>(outT + (size_t)node * 32 + c0) = o;
    }
}

// ---------------- fused: hop-4 pull (+relu) -> emb, + final GEMM Wf -> logits (32 n/blk) ----
__global__ __launch_bounds__(256)
void pullgemmF_k(const float* __restrict__ in, const int* __restrict__ csr,
                 const int* __restrict__ cursor, const float* __restrict__ dinv,
                 const float* __restrict__ b2, const float* __restrict__ Wf,
                 const float* __restrict__ bf, float* __restrict__ embOut,
                 float* __restrict__ logits) {
    __shared__ float es[32][36];
    __shared__ float Wfs[32][40];
    __shared__ float bfs[40];
    const int t = threadIdx.x;
    for (int i = t; i < 32 * 40 / 4; i += 256)
        reinterpret_cast<float4*>(&Wfs[0][0])[i] = reinterpret_cast<const float4*>(Wf)[i];
    if (t < 40) bfs[t] = bf[t];
    const int nodeBase = blockIdx.x * 32;
    // pull phase: 8 lanes/node, 32 nodes, single pass
    {
        const int nb = t / 8;
        const int node = nodeBase + nb;
        const int col = (t % 8) * 4;
        float4 r = make_float4(0.f, 0.f, 0.f, 0.f);
        if (node < NN) {
            const int beg = (node == 0) ? 0 : cursor[node - 1];
            const int end = cursor[node];
            float4 a0 = *reinterpret_cast<const float4*>(in + (size_t)node * 32 + col);
            float4 a1 = make_float4(0.f, 0.f, 0.f, 0.f);
            float4 a2 = make_float4(0.f, 0.f, 0.f, 0.f);
            float4 a3 = make_float4(0.f, 0.f, 0.f, 0.f);
            int k = beg;
            for (; k + 3 < end; k += 4) {
                int s0 = csr[k], s1 = csr[k + 1], s2 = csr[k + 2], s3 = csr[k + 3];
                float4 v0 = *reinterpret_cast<const float4*>(in + (size_t)s0 * 32 + col);
                float4 v1 = *reinterpret_cast<const float4*>(in + (size_t)s1 * 32 + col);
                float4 v2 = *reinterpret_cast<const float4*>(in + (size_t)s2 * 32 + col);
                float4 v3 = *reinterpret_cast<const float4*>(in + (size_t)s3 * 32 + col);
                a0.x += v0.x; a0.y += v0.y; a0.z += v0.z; a0.w += v0.w;
                a1.x += v1.x; a1.y += v1.y; a1.z += v1.z; a1.w += v1.w;
                a2.x += v2.x; a2.y += v2.y; a2.z += v2.z; a2.w += v2.w;
                a3.x += v3.x; a3.y += v3.y; a3.z += v3.z; a3.w += v3.w;
            }
            for (; k < end; ++k) {
                int s0 = csr[k];
                float4 v0 = *reinterpret_cast<const float4*>(in + (size_t)s0 * 32 + col);
                a0.x += v0.x; a0.y += v0.y; a0.z += v0.z; a0.w += v0.w;
            }
            const float sc = dinv[node];
            const float4 bv = *reinterpret_cast<const float4*>(b2 + col);
            r.x = fmaxf((a0.x + a1.x + a2.x + a3.x) * sc + bv.x, 0.f);
            r.y = fmaxf((a0.y + a1.y + a2.y + a3.y) * sc + bv.y, 0.f);
            r.z = fmaxf((a0.z + a1.z + a2.z + a3.z) * sc + bv.z, 0.f);
            r.w = fmaxf((a0.w + a1.w + a2.w + a3.w) * sc + bv.w, 0.f);
            *reinterpret_cast<float4*>(embOut + (size_t)node * 32 + col) = r;
        }
        *reinterpret_cast<float4*>(&es[nb][col]) = r;
    }
    __syncthreads();
    // GEMM: 32 rows x 40 cols, thread owns (row, 5 cols)
    const int r = t / 8;
    const int c0 = (t % 8) * 5;
    float acc[5];
    #pragma unroll
    for (int j = 0; j < 5; ++j) acc[j] = bfs[c0 + j];
    #pragma unroll 4
    for (int k = 0; k < 32; k += 4) {
        float4 av = *reinterpret_cast<const float4*>(&es[r][k]);
        #pragma unroll
        for (int kk = 0; kk < 4; ++kk) {
            float a = (&av.x)[kk];
            #pragma unroll
            for (int j = 0; j < 5; ++j)
                acc[j] = fmaf(a, Wfs[k + kk][c0 + j], acc[j]);
        }
    }
    const int node = nodeBase + r;
    if (node < NN) {
        float* lp = logits + (size_t)node * 40 + c0;
        #pragma unroll
        for (int j = 0; j < 5; ++j) lp[j] = acc[j];
    }
}

extern "C" void kernel_launch(void* const* d_in, const int* in_sizes, int n_in,
                              void* d_out, int out_size, void* d_ws, size_t ws_size,
                              hipStream_t stream) {
    const float* x  = (const float*)d_in[0];
    const int*   ei = (const int*)d_in[1];
    const float* W1 = (const float*)d_in[2];
    const float* b1 = (const float*)d_in[3];
    const float* W2 = (const float*)d_in[4];
    const float* b2 = (const float*)d_in[5];
    const float* Wf = (const float*)d_in[6];
    const float* bf = (const float*)d_in[7];

    float* out    = (float*)d_out;
    float* embOut = out;                       // [N, 32]
    float* logits = out + (size_t)NN * H2_F;   // [N, 40]

    const int* src = ei;        // edge_index[0]
    const int* dst = ei + NE;   // edge_index[1]

    // workspace layout (16B-aligned blocks) — round-7 verbatim
    float* ws       = (float*)d_ws;
    float* dinv     = ws;                           // NN f32
    int*   cursor   = (int*)(ws + NN);              // NN i32
    int*   csr      = cursor + NN;                  // NE i32
    int*   gCursor  = csr + NE;                     // 512 i32
    int*   segBase  = gCursor + 512;                // 512 i32
    float* bufA     = (float*)(segBase + 512);      // NN*64 f32
    float* bufB     = bufA + (size_t)NN * 64;       // NN*64 f32
    uint2* pairs    = (uint2*)bufB;                 // 12.6MB, dead before pull #1

    // ---- CSR build + dinv (bucketized, XCD-local writes) ----
    initcur_k<<<cdiv(NBKT, 256), 256, 0, stream>>>(gCursor);
    binA_k<<<NCH, 256, 0, stream>>>(src, dst, pairs, gCursor);
    segscan_k<<<1, 512, 0, stream>>>(gCursor, segBase);
    binB_k<<<NBKT, 256, 0, stream>>>(pairs, gCursor, segBase, cursor, dinv, csr);

    // ---- layer 1 ----
    gemm_tile_k<IN_F, H1_F, 16, 4, 256, false, true>
        <<<cdiv(NN, 64), 256, 0, stream>>>(x, W1, nullptr, dinv, bufA);          // t = dinv*(xW1)
    pull4_k<H1_F>
        <<<cdiv(NN, 256 / (H1_F / 4)), 256, 0, stream>>>(bufA, csr, cursor, dinv, bufB);  // v
    pullgemm2_k
        <<<cdiv(NN, 32), 256, 0, stream>>>(bufB, csr, cursor, dinv, b1, W2, bufA);        // t2

    // ---- layer 2 ----
    pull4_k<H2_F>
        <<<cdiv(NN, 256 / (H2_F / 4)), 256, 0, stream>>>(bufA, csr, cursor, dinv, bufB);  // u
    pullgemmF_k
        <<<cdiv(NN, 32), 256, 0, stream>>>(bufB, csr, cursor, dinv, b2, Wf, bf, embOut, logits);
}

// Round 13
// 221.404 us; speedup vs baseline: 1.3297x; 1.0468x over previous
//
#include <hip/hip_runtime.h>

// Problem constants (from reference)
#define NN 50000
#define NE 800000
#define IN_F 128
#define H1_F 64
#define H2_F 32
#define OUT_F 40

// bucketized CSR build
#define BSH 7                    // bucket = dst >> 7  (128 nodes per bucket)
#define NBKT 391                 // ceil(50000 / 128)
#define CAPA 4032                // per-bucket capacity (avg 2046; 12.6MB total, aliases bufB)
#define CHUNK 4096               // edges per binA block
#define NCH ((NE + CHUNK - 1) / CHUNK)   // 196

static inline int cdiv(int a, int b) { return (a + b - 1) / b; }

// bf16 <-> f32 (round-to-nearest-even store)
__device__ __forceinline__ unsigned short f2bf(float f) {
    unsigned u = __float_as_uint(f);
    u += 0x7FFFu + ((u >> 16) & 1u);
    return (unsigned short)(u >> 16);
}
__device__ __forceinline__ float bf2f(unsigned short h) {
    return __uint_as_float(((unsigned)h) << 16);
}
__device__ __forceinline__ float4 bf4_to_f4(ushort4 h) {
    return make_float4(bf2f(h.x), bf2f(h.y), bf2f(h.z), bf2f(h.w));
}

// ---------------- CSR build: two-phase bucketized counting sort (round-7 verbatim) ----------
__global__ void initcur_k(int* __restrict__ gCursor) {
    int b = blockIdx.x * 256 + threadIdx.x;
    if (b < NBKT) gCursor[b] = b * CAPA;
}

__global__ __launch_bounds__(256)
void binA_k(const int* __restrict__ src, const int* __restrict__ dst,
            uint2* __restrict__ pairs, int* __restrict__ gCursor) {
    __shared__ int hist[512], incl[512], runSt[512], lcur[512], baseSh[512];
    __shared__ uint2 stage[CHUNK];
    const int t = threadIdx.x;
    const int e0 = blockIdx.x * CHUNK;
    const int n = min(CHUNK, NE - e0);

    hist[t] = 0; hist[t + 256] = 0;
    __syncthreads();
    for (int i = t; i < n; i += 256) {
        int d = dst[e0 + i];
        atomicAdd(&hist[d >> BSH], 1);
    }
    __syncthreads();
    incl[t] = hist[t]; incl[t + 256] = hist[t + 256];
    __syncthreads();
    for (int off = 1; off < 512; off <<= 1) {
        int v0 = (t >= off) ? incl[t - off] : 0;
        int v1 = (t + 256 >= off) ? incl[t + 256 - off] : 0;
        __syncthreads();
        incl[t] += v0; incl[t + 256] += v1;
        __syncthreads();
    }
    runSt[t] = incl[t] - hist[t];   runSt[t + 256] = incl[t + 256] - hist[t + 256];
    lcur[t]  = runSt[t];            lcur[t + 256]  = runSt[t + 256];
    __syncthreads();
    for (int i = t; i < n; i += 256) {
        int s = src[e0 + i], d = dst[e0 + i];
        int b = d >> BSH;
        int p = atomicAdd(&lcur[b], 1);
        stage[p] = make_uint2((unsigned)s, (unsigned)d);
    }
    for (int b = t; b < NBKT; b += 256) {
        int c = hist[b];
        baseSh[b] = c ? atomicAdd(&gCursor[b], c) : 0;
    }
    __syncthreads();
    for (int i = t; i < n; i += 256) {
        uint2 p = stage[i];
        int b = (int)(p.y >> BSH);
        int gp = baseSh[b] + (i - runSt[b]);
        if (gp < (b + 1) * CAPA) pairs[gp] = p;
    }
}

__global__ __launch_bounds__(512)
void segscan_k(const int* __restrict__ gCursor, int* __restrict__ segBase) {
    __shared__ int sh[512], orig[512];
    int t = threadIdx.x;
    int c = 0;
    if (t < NBKT) {
        c = gCursor[t] - t * CAPA;
        c = max(0, min(c, CAPA));
    }
    sh[t] = c; orig[t] = c;
    __syncthreads();
    for (int off = 1; off < 512; off <<= 1) {
        int v = (t >= off) ? sh[t - off] : 0;
        __syncthreads();
        sh[t] += v;
        __syncthreads();
    }
    if (t < NBKT) segBase[t] = sh[t] - orig[t];
}

__global__ __launch_bounds__(256)
void binB_k(const uint2* __restrict__ pairs, const int* __restrict__ gCursor,
            const int* __restrict__ segBase, int* __restrict__ cursor,
            float* __restrict__ dinv, int* __restrict__ csr) {
    const int b = blockIdx.x;
    const int nodeBase = b << BSH;
    const int nNodes = min(128, NN - nodeBase);
    int count = gCursor[b] - b * CAPA;
    count = max(0, min(count, CAPA));
    const int seg = segBase[b];
    __shared__ int hist[128], incl[128], lcur[128];
    const int t = threadIdx.x;
    if (t < 128) hist[t] = 0;
    __syncthreads();
    const uint2* bp = pairs + (size_t)b * CAPA;
    for (int i = t; i < count; i += 256) {
        int d = (int)bp[i].y - nodeBase;
        atomicAdd(&hist[d], 1);
    }
    __syncthreads();
    if (t < 128) incl[t] = hist[t];
    __syncthreads();
    for (int off = 1; off < 128; off <<= 1) {
        int v = (t < 128 && t >= off) ? incl[t - off] : 0;
        __syncthreads();
        if (t < 128) incl[t] += v;
        __syncthreads();
    }
    if (t < nNodes) {
        cursor[nodeBase + t] = seg + incl[t];
        dinv[nodeBase + t]   = rsqrtf((float)hist[t] + 1.0f);
        lcur[t] = seg + incl[t] - hist[t];
    }
    __syncthreads();
    for (int i = t; i < count; i += 256) {
        uint2 p = bp[i];
        int d = (int)p.y - nodeBase;
        int pos = atomicAdd(&lcur[d], 1);
        csr[pos] = (int)p.x;
    }
}

// ---------------- register-tiled GEMM; OBF16 stores output as bf16 -------------------------
template<int K, int F, int CT, int RPT, int BLOCK, bool BIAS, bool SCALE, bool OBF16>
__global__ __launch_bounds__(BLOCK)
void gemm_tile_k(const float* __restrict__ X, const float* __restrict__ W,
                 const float* __restrict__ b, const float* __restrict__ dinv,
                 void* __restrict__ Yv) {
    constexpr int RT = BLOCK / CT;
    constexpr int TR = RT * RPT;
    constexpr int KT = 32;
    constexpr int KPAD = KT + 1;
    __shared__ float Xs[TR][KPAD];
    __shared__ float Wsh[KT][F];
    const int rowBase = blockIdx.x * TR;
    const int tc = threadIdx.x % CT;
    const int tr = threadIdx.x / CT;

    float acc[RPT][4];
    #pragma unroll
    for (int i = 0; i < RPT; ++i)
        #pragma unroll
        for (int j = 0; j < 4; ++j) acc[i][j] = 0.0f;

    for (int k0 = 0; k0 < K; k0 += KT) {
        constexpr int XL4 = TR * KT / 4;
        for (int l = threadIdx.x; l < XL4; l += BLOCK) {
            int r  = l / (KT / 4);
            int kk = (l % (KT / 4)) * 4;
            float4 v = make_float4(0.f, 0.f, 0.f, 0.f);
            int gr = rowBase + r;
            if (gr < NN) v = *reinterpret_cast<const float4*>(X + (size_t)gr * K + k0 + kk);
            Xs[r][kk + 0] = v.x; Xs[r][kk + 1] = v.y;
            Xs[r][kk + 2] = v.z; Xs[r][kk + 3] = v.w;
        }
        constexpr int WL4 = KT * F / 4;
        for (int l = threadIdx.x; l < WL4; l += BLOCK) {
            int kk = l / (F / 4);
            int c  = (l % (F / 4)) * 4;
            *reinterpret_cast<float4*>(&Wsh[kk][c]) =
                *reinterpret_cast<const float4*>(W + (size_t)(k0 + kk) * F + c);
        }
        __syncthreads();
        #pragma unroll
        for (int kk = 0; kk < KT; ++kk) {
            float wv[4];
            *reinterpret_cast<float4*>(wv) = *reinterpret_cast<const float4*>(&Wsh[kk][tc * 4]);
            #pragma unroll
            for (int i = 0; i < RPT; ++i) {
                float a = Xs[tr * RPT + i][kk];
                acc[i][0] = fmaf(a, wv[0], acc[i][0]);
                acc[i][1] = fmaf(a, wv[1], acc[i][1]);
                acc[i][2] = fmaf(a, wv[2], acc[i][2]);
                acc[i][3] = fmaf(a, wv[3], acc[i][3]);
            }
        }
        __syncthreads();
    }
    #pragma unroll
    for (int i = 0; i < RPT; ++i) {
        int gr = rowBase + tr * RPT + i;
        if (gr < NN) {
            float sc = SCALE ? dinv[gr] : 1.0f;
            float4 v;
            v.x = acc[i][0]; v.y = acc[i][1]; v.z = acc[i][2]; v.w = acc[i][3];
            if (BIAS) {
                v.x += b[tc * 4 + 0]; v.y += b[tc * 4 + 1];
                v.z += b[tc * 4 + 2]; v.w += b[tc * 4 + 3];
            }
            v.x *= sc; v.y *= sc; v.z *= sc; v.w *= sc;
            if (OBF16) {
                ushort4 o;
                o.x = f2bf(v.x); o.y = f2bf(v.y); o.z = f2bf(v.z); o.w = f2bf(v.w);
                *reinterpret_cast<ushort4*>((unsigned short*)Yv + (size_t)gr * F + tc * 4) = o;
            } else {
                *reinterpret_cast<float4*>((float*)Yv + (size_t)gr * F + tc * 4) = v;
            }
        }
    }
}

// ---------------- pull (bf16 input): out[d] = dinv_d^2 * (in[d] + sum in[s]), f32 out -------
template<int F>
__global__ __launch_bounds__(256)
void pull4bf_k(const unsigned short* __restrict__ in, const int* __restrict__ csr,
               const int* __restrict__ cursor, const float* __restrict__ dinv,
               float* __restrict__ out) {
    constexpr int LPN = F / 4;
    constexpr int NPB = 256 / LPN;
    const int t = threadIdx.x;
    const int node = blockIdx.x * NPB + t / LPN;
    const int col  = (t % LPN) * 4;
    if (node >= NN) return;
    const int beg = (node == 0) ? 0 : cursor[node - 1];
    const int end = cursor[node];
    float4 a0 = bf4_to_f4(*reinterpret_cast<const ushort4*>(in + (size_t)node * F + col));  // self
    float4 a1 = make_float4(0.f, 0.f, 0.f, 0.f);
    float4 a2 = make_float4(0.f, 0.f, 0.f, 0.f);
    float4 a3 = make_float4(0.f, 0.f, 0.f, 0.f);
    int k = beg;
    for (; k + 3 < end; k += 4) {
        int s0 = csr[k], s1 = csr[k + 1], s2 = csr[k + 2], s3 = csr[k + 3];
        ushort4 h0 = *reinterpret_cast<const ushort4*>(in + (size_t)s0 * F + col);
        ushort4 h1 = *reinterpret_cast<const ushort4*>(in + (size_t)s1 * F + col);
        ushort4 h2 = *reinterpret_cast<const ushort4*>(in + (size_t)s2 * F + col);
        ushort4 h3 = *reinterpret_cast<const ushort4*>(in + (size_t)s3 * F + col);
        float4 v0 = bf4_to_f4(h0), v1 = bf4_to_f4(h1), v2 = bf4_to_f4(h2), v3 = bf4_to_f4(h3);
        a0.x += v0.x; a0.y += v0.y; a0.z += v0.z; a0.w += v0.w;
        a1.x += v1.x; a1.y += v1.y; a1.z += v1.z; a1.w += v1.w;
        a2.x += v2.x; a2.y += v2.y; a2.z += v2.z; a2.w += v2.w;
        a3.x += v3.x; a3.y += v3.y; a3.z += v3.z; a3.w += v3.w;
    }
    for (; k < end; ++k) {
        int s0 = csr[k];
        float4 v0 = bf4_to_f4(*reinterpret_cast<const ushort4*>(in + (size_t)s0 * F + col));
        a0.x += v0.x; a0.y += v0.y; a0.z += v0.z; a0.w += v0.w;
    }
    float sc = dinv[node]; sc *= sc;
    float4 r;
    r.x = (a0.x + a1.x + a2.x + a3.x) * sc;
    r.y = (a0.y + a1.y + a2.y + a3.y) * sc;
    r.z = (a0.z + a1.z + a2.z + a3.z) * sc;
    r.w = (a0.w + a1.w + a2.w + a3.w) * sc;
    *reinterpret_cast<float4*>(out + (size_t)node * F + col) = r;
}

// ---------------- fused: hop-2 pull f32 (+relu) + GEMM W2 + dinv scale -> bf16 t2 ----------
// h = relu(dinv_d*(v[d]+sum v[s]) + b1);  t2[d] = dinv_d * (h @ W2)   [64 -> 32]
__global__ __launch_bounds__(256)
void pullgemm2_k(const float* __restrict__ in, const int* __restrict__ csr,
                 const int* __restrict__ cursor, const float* __restrict__ dinv,
                 const float* __restrict__ b1, const float* __restrict__ W2,
                 unsigned short* __restrict__ outT) {
    __shared__ float hs[32][68];
    __shared__ float W2s[64][32];
    const int t = threadIdx.x;
    for (int i = t; i < 64 * 32 / 4; i += 256)
        reinterpret_cast<float4*>(&W2s[0][0])[i] = reinterpret_cast<const float4*>(W2)[i];
    const int nodeBase = blockIdx.x * 32;
    #pragma unroll
    for (int pass = 0; pass < 2; ++pass) {
        const int nb = pass * 16 + t / 16;
        const int node = nodeBase + nb;
        const int col = (t % 16) * 4;
        float4 r = make_float4(0.f, 0.f, 0.f, 0.f);
        if (node < NN) {
            const int beg = (node == 0) ? 0 : cursor[node - 1];
            const int end = cursor[node];
            float4 a0 = *reinterpret_cast<const float4*>(in + (size_t)node * 64 + col);
            float4 a1 = make_float4(0.f, 0.f, 0.f, 0.f);
            float4 a2 = make_float4(0.f, 0.f, 0.f, 0.f);
            float4 a3 = make_float4(0.f, 0.f, 0.f, 0.f);
            int k = beg;
            for (; k + 3 < end; k += 4) {
                int s0 = csr[k], s1 = csr[k + 1], s2 = csr[k + 2], s3 = csr[k + 3];
                float4 v0 = *reinterpret_cast<const float4*>(in + (size_t)s0 * 64 + col);
                float4 v1 = *reinterpret_cast<const float4*>(in + (size_t)s1 * 64 + col);
                float4 v2 = *reinterpret_cast<const float4*>(in + (size_t)s2 * 64 + col);
                float4 v3 = *reinterpret_cast<const float4*>(in + (size_t)s3 * 64 + col);
                a0.x += v0.x; a0.y += v0.y; a0.z += v0.z; a0.w += v0.w;
                a1.x += v1.x; a1.y += v1.y; a1.z += v1.z; a1.w += v1.w;
                a2.x += v2.x; a2.y += v2.y; a2.z += v2.z; a2.w += v2.w;
                a3.x += v3.x; a3.y += v3.y; a3.z += v3.z; a3.w += v3.w;
            }
            for (; k < end; ++k) {
                int s0 = csr[k];
                float4 v0 = *reinterpret_cast<const float4*>(in + (size_t)s0 * 64 + col);
                a0.x += v0.x; a0.y += v0.y; a0.z += v0.z; a0.w += v0.w;
            }
            const float sc = dinv[node];
            const float4 bv = *reinterpret_cast<const float4*>(b1 + col);
            r.x = fmaxf((a0.x + a1.x + a2.x + a3.x) * sc + bv.x, 0.f);
            r.y = fmaxf((a0.y + a1.y + a2.y + a3.y) * sc + bv.y, 0.f);
            r.z = fmaxf((a0.z + a1.z + a2.z + a3.z) * sc + bv.z, 0.f);
            r.w = fmaxf((a0.w + a1.w + a2.w + a3.w) * sc + bv.w, 0.f);
        }
        *reinterpret_cast<float4*>(&hs[nb][col]) = r;
    }
    __syncthreads();
    // GEMM: 32 rows x 32 cols, thread owns (row, 4 cols)
    const int r = t / 8;
    const int c0 = (t % 8) * 4;
    float acc[4] = {0.f, 0.f, 0.f, 0.f};
    #pragma unroll 4
    for (int k = 0; k < 64; k += 4) {
        float4 av = *reinterpret_cast<const float4*>(&hs[r][k]);
        #pragma unroll
        for (int kk = 0; kk < 4; ++kk) {
            float a = (&av.x)[kk];
            float4 w = *reinterpret_cast<const float4*>(&W2s[k + kk][c0]);
            acc[0] = fmaf(a, w.x, acc[0]); acc[1] = fmaf(a, w.y, acc[1]);
            acc[2] = fmaf(a, w.z, acc[2]); acc[3] = fmaf(a, w.w, acc[3]);
        }
    }
    const int node = nodeBase + r;
    if (node < NN) {
        const float sc = dinv[node];
        ushort4 o;
        o.x = f2bf(acc[0] * sc); o.y = f2bf(acc[1] * sc);
        o.z = f2bf(acc[2] * sc); o.w = f2bf(acc[3] * sc);
        *reinterpret_cast<ushort4*>(outT + (size_t)node * 32 + c0) = o;
    }
}

// ---------------- fused: hop-4 pull f32 (+relu) -> emb, + final GEMM Wf -> logits ----------
__global__ __launch_bounds__(256)
void pullgemmF_k(const float* __restrict__ in, const int* __restrict__ csr,
                 const int* __restrict__ cursor, const float* __restrict__ dinv,
                 const float* __restrict__ b2, const float* __restrict__ Wf,
                 const float* __restrict__ bf, float* __restrict__ embOut,
                 float* __restrict__ logits) {
    __shared__ float es[32][36];
    __shared__ float Wfs[32][40];
    __shared__ float bfs[40];
    const int t = threadIdx.x;
    for (int i = t; i < 32 * 40 / 4; i += 256)
        reinterpret_cast<float4*>(&Wfs[0][0])[i] = reinterpret_cast<const float4*>(Wf)[i];
    if (t < 40) bfs[t] = bf[t];
    const int nodeBase = blockIdx.x * 32;
    // pull phase: 8 lanes/node, 32 nodes, single pass
    {
        const int nb = t / 8;
        const int node = nodeBase + nb;
        const int col = (t % 8) * 4;
        float4 r = make_float4(0.f, 0.f, 0.f, 0.f);
        if (node < NN) {
            const int beg = (node == 0) ? 0 : cursor[node - 1];
            const int end = cursor[node];
            float4 a0 = *reinterpret_cast<const float4*>(in + (size_t)node * 32 + col);
            float4 a1 = make_float4(0.f, 0.f, 0.f, 0.f);
            float4 a2 = make_float4(0.f, 0.f, 0.f, 0.f);
            float4 a3 = make_float4(0.f, 0.f, 0.f, 0.f);
            int k = beg;
            for (; k + 3 < end; k += 4) {
                int s0 = csr[k], s1 = csr[k + 1], s2 = csr[k + 2], s3 = csr[k + 3];
                float4 v0 = *reinterpret_cast<const float4*>(in + (size_t)s0 * 32 + col);
                float4 v1 = *reinterpret_cast<const float4*>(in + (size_t)s1 * 32 + col);
                float4 v2 = *reinterpret_cast<const float4*>(in + (size_t)s2 * 32 + col);
                float4 v3 = *reinterpret_cast<const float4*>(in + (size_t)s3 * 32 + col);
                a0.x += v0.x; a0.y += v0.y; a0.z += v0.z; a0.w += v0.w;
                a1.x += v1.x; a1.y += v1.y; a1.z += v1.z; a1.w += v1.w;
                a2.x += v2.x; a2.y += v2.y; a2.z += v2.z; a2.w += v2.w;
                a3.x += v3.x; a3.y += v3.y; a3.z += v3.z; a3.w += v3.w;
            }
            for (; k < end; ++k) {
                int s0 = csr[k];
                float4 v0 = *reinterpret_cast<const float4*>(in + (size_t)s0 * 32 + col);
                a0.x += v0.x; a0.y += v0.y; a0.z += v0.z; a0.w += v0.w;
            }
            const float sc = dinv[node];
            const float4 bv = *reinterpret_cast<const float4*>(b2 + col);
            r.x = fmaxf((a0.x + a1.x + a2.x + a3.x) * sc + bv.x, 0.f);
            r.y = fmaxf((a0.y + a1.y + a2.y + a3.y) * sc + bv.y, 0.f);
            r.z = fmaxf((a0.z + a1.z + a2.z + a3.z) * sc + bv.z, 0.f);
            r.w = fmaxf((a0.w + a1.w + a2.w + a3.w) * sc + bv.w, 0.f);
            *reinterpret_cast<float4*>(embOut + (size_t)node * 32 + col) = r;
        }
        *reinterpret_cast<float4*>(&es[nb][col]) = r;
    }
    __syncthreads();
    // GEMM: 32 rows x 40 cols, thread owns (row, 5 cols)
    const int r = t / 8;
    const int c0 = (t % 8) * 5;
    float acc[5];
    #pragma unroll
    for (int j = 0; j < 5; ++j) acc[j] = bfs[c0 + j];
    #pragma unroll 4
    for (int k = 0; k < 32; k += 4) {
        float4 av = *reinterpret_cast<const float4*>(&es[r][k]);
        #pragma unroll
        for (int kk = 0; kk < 4; ++kk) {
            float a = (&av.x)[kk];
            #pragma unroll
            for (int j = 0; j < 5; ++j)
                acc[j] = fmaf(a, Wfs[k + kk][c0 + j], acc[j]);
        }
    }
    const int node = nodeBase + r;
    if (node < NN) {
        float* lp = logits + (size_t)node * 40 + c0;
        #pragma unroll
        for (int j = 0; j < 5; ++j) lp[j] = acc[j];
    }
}

extern "C" void kernel_launch(void* const* d_in, const int* in_sizes, int n_in,
                              void* d_out, int out_size, void* d_ws, size_t ws_size,
                              hipStream_t stream) {
    const float* x  = (const float*)d_in[0];
    const int*   ei = (const int*)d_in[1];
    const float* W1 = (const float*)d_in[2];
    const float* b1 = (const float*)d_in[3];
    const float* W2 = (const float*)d_in[4];
    const float* b2 = (const float*)d_in[5];
    const float* Wf = (const float*)d_in[6];
    const float* bf = (const float*)d_in[7];

    float* out    = (float*)d_out;
    float* embOut = out;                       // [N, 32]
    float* logits = out + (size_t)NN * H2_F;   // [N, 40]

    const int* src = ei;        // edge_index[0]
    const int* dst = ei + NE;   // edge_index[1]

    // workspace layout (16B-aligned blocks)
    float* ws       = (float*)d_ws;
    float* dinv     = ws;                           // NN f32
    int*   cursor   = (int*)(ws + NN);              // NN i32
    int*   csr      = cursor + NN;                  // NE i32
    int*   gCursor  = csr + NE;                     // 512 i32
    int*   segBase  = gCursor + 512;                // 512 i32
    float* bufA     = (float*)(segBase + 512);      // NN*64 f32 region: t (bf16), later t2 (bf16)
    float* bufB     = bufA + (size_t)NN * 64;       // NN*64 f32 region: v (f32), later u (f32)
    uint2* pairs    = (uint2*)bufB;                 // 12.6MB, dead before pull #1 writes bufB
    unsigned short* tbf  = (unsigned short*)bufA;   // t  [NN,64] bf16 (6.4MB)
    unsigned short* t2bf = (unsigned short*)bufA;   // t2 [NN,32] bf16 (3.2MB, reuses after t dead)

    // ---- CSR build + dinv (bucketized, XCD-local writes) ----
    initcur_k<<<cdiv(NBKT, 256), 256, 0, stream>>>(gCursor);
    binA_k<<<NCH, 256, 0, stream>>>(src, dst, pairs, gCursor);
    segscan_k<<<1, 512, 0, stream>>>(gCursor, segBase);
    binB_k<<<NBKT, 256, 0, stream>>>(pairs, gCursor, segBase, cursor, dinv, csr);

    // ---- layer 1 ----
    gemm_tile_k<IN_F, H1_F, 16, 4, 256, false, true, true>
        <<<cdiv(NN, 64), 256, 0, stream>>>(x, W1, nullptr, dinv, tbf);           // t = dinv*(xW1) -> bf16
    pull4bf_k<H1_F>
        <<<cdiv(NN, 256 / (H1_F / 4)), 256, 0, stream>>>(tbf, csr, cursor, dinv, bufB);   // v (f32)
    pullgemm2_k
        <<<cdiv(NN, 32), 256, 0, stream>>>(bufB, csr, cursor, dinv, b1, W2, t2bf);        // t2 -> bf16

    // ---- layer 2 ----
    pull4bf_k<H2_F>
        <<<cdiv(NN, 256 / (H2_F / 4)), 256, 0, stream>>>(t2bf, csr, cursor, dinv, bufB);  // u (f32)
    pullgemmF_k
        <<<cdiv(NN, 32), 256, 0, stream>>>(bufB, csr, cursor, dinv, b2, Wf, bf, embOut, logits);
}

// Round 14
// 210.094 us; speedup vs baseline: 1.4013x; 1.0538x over previous
//
#include <hip/hip_runtime.h>

// Problem constants (from reference)
#define NN 50000
#define NE 800000
#define IN_F 128
#define H1_F 64
#define H2_F 32
#define OUT_F 40

// bucketized CSR build
#define BSH 7                    // bucket = dst >> 7  (128 nodes per bucket)
#define NBKT 391                 // ceil(50000 / 128)
#define CAPA 4032                // per-bucket capacity (avg 2046; 12.6MB total, aliases bufB)
#define CHUNK 4096               // edges per binA block
#define NCH ((NE + CHUNK - 1) / CHUNK)   // 196

static inline int cdiv(int a, int b) { return (a + b - 1) / b; }

// bf16 <-> f32 (round-to-nearest-even store)
__device__ __forceinline__ unsigned short f2bf(float f) {
    unsigned u = __float_as_uint(f);
    u += 0x7FFFu + ((u >> 16) & 1u);
    return (unsigned short)(u >> 16);
}
__device__ __forceinline__ float bf2f(unsigned short h) {
    return __uint_as_float(((unsigned)h) << 16);
}
__device__ __forceinline__ float4 bf4_to_f4(ushort4 h) {
    return make_float4(bf2f(h.x), bf2f(h.y), bf2f(h.z), bf2f(h.w));
}

// ---------------- CSR build: two-phase bucketized counting sort ----------------
__global__ void initcur_k(int* __restrict__ gCursor) {
    int b = blockIdx.x * 256 + threadIdx.x;
    if (b < NBKT) gCursor[b] = b * CAPA;
}

__global__ __launch_bounds__(256)
void binA_k(const int* __restrict__ src, const int* __restrict__ dst,
            uint2* __restrict__ pairs, int* __restrict__ gCursor) {
    __shared__ int hist[512], incl[512], runSt[512], lcur[512], baseSh[512];
    __shared__ uint2 stage[CHUNK];
    const int t = threadIdx.x;
    const int e0 = blockIdx.x * CHUNK;
    const int n = min(CHUNK, NE - e0);

    hist[t] = 0; hist[t + 256] = 0;
    __syncthreads();
    for (int i = t; i < n; i += 256) {
        int d = dst[e0 + i];
        atomicAdd(&hist[d >> BSH], 1);
    }
    __syncthreads();
    incl[t] = hist[t]; incl[t + 256] = hist[t + 256];
    __syncthreads();
    for (int off = 1; off < 512; off <<= 1) {
        int v0 = (t >= off) ? incl[t - off] : 0;
        int v1 = (t + 256 >= off) ? incl[t + 256 - off] : 0;
        __syncthreads();
        incl[t] += v0; incl[t + 256] += v1;
        __syncthreads();
    }
    runSt[t] = incl[t] - hist[t];   runSt[t + 256] = incl[t + 256] - hist[t + 256];
    lcur[t]  = runSt[t];            lcur[t + 256]  = runSt[t + 256];
    __syncthreads();
    for (int i = t; i < n; i += 256) {
        int s = src[e0 + i], d = dst[e0 + i];
        int b = d >> BSH;
        int p = atomicAdd(&lcur[b], 1);
        stage[p] = make_uint2((unsigned)s, (unsigned)d);
    }
    for (int b = t; b < NBKT; b += 256) {
        int c = hist[b];
        baseSh[b] = c ? atomicAdd(&gCursor[b], c) : 0;
    }
    __syncthreads();
    for (int i = t; i < n; i += 256) {
        uint2 p = stage[i];
        int b = (int)(p.y >> BSH);
        int gp = baseSh[b] + (i - runSt[b]);
        if (gp < (b + 1) * CAPA) pairs[gp] = p;
    }
}

__global__ __launch_bounds__(512)
void segscan_k(const int* __restrict__ gCursor, int* __restrict__ segBase) {
    __shared__ int sh[512], orig[512];
    int t = threadIdx.x;
    int c = 0;
    if (t < NBKT) {
        c = gCursor[t] - t * CAPA;
        c = max(0, min(c, CAPA));
    }
    sh[t] = c; orig[t] = c;
    __syncthreads();
    for (int off = 1; off < 512; off <<= 1) {
        int v = (t >= off) ? sh[t - off] : 0;
        __syncthreads();
        sh[t] += v;
        __syncthreads();
    }
    if (t < NBKT) segBase[t] = sh[t] - orig[t];
}

__global__ __launch_bounds__(256)
void binB_k(const uint2* __restrict__ pairs, const int* __restrict__ gCursor,
            const int* __restrict__ segBase, int* __restrict__ cursor,
            float* __restrict__ dinv, int* __restrict__ csr) {
    const int b = blockIdx.x;
    const int nodeBase = b << BSH;
    const int nNodes = min(128, NN - nodeBase);
    int count = gCursor[b] - b * CAPA;
    count = max(0, min(count, CAPA));
    const int seg = segBase[b];
    __shared__ int hist[128], incl[128], lcur[128];
    const int t = threadIdx.x;
    if (t < 128) hist[t] = 0;
    __syncthreads();
    const uint2* bp = pairs + (size_t)b * CAPA;
    for (int i = t; i < count; i += 256) {
        int d = (int)bp[i].y - nodeBase;
        atomicAdd(&hist[d], 1);
    }
    __syncthreads();
    if (t < 128) incl[t] = hist[t];
    __syncthreads();
    for (int off = 1; off < 128; off <<= 1) {
        int v = (t < 128 && t >= off) ? incl[t - off] : 0;
        __syncthreads();
        if (t < 128) incl[t] += v;
        __syncthreads();
    }
    if (t < nNodes) {
        cursor[nodeBase + t] = seg + incl[t];
        dinv[nodeBase + t]   = rsqrtf((float)hist[t] + 1.0f);
        lcur[t] = seg + incl[t] - hist[t];
    }
    __syncthreads();
    for (int i = t; i < count; i += 256) {
        uint2 p = bp[i];
        int d = (int)p.y - nodeBase;
        int pos = atomicAdd(&lcur[d], 1);
        csr[pos] = (int)p.x;
    }
}

// ---------------- register-tiled GEMM; OBF16 stores output as bf16 -------------------------
template<int K, int F, int CT, int RPT, int BLOCK, bool BIAS, bool SCALE, bool OBF16>
__global__ __launch_bounds__(BLOCK)
void gemm_tile_k(const float* __restrict__ X, const float* __restrict__ W,
                 const float* __restrict__ b, const float* __restrict__ dinv,
                 void* __restrict__ Yv) {
    constexpr int RT = BLOCK / CT;
    constexpr int TR = RT * RPT;
    constexpr int KT = 32;
    constexpr int KPAD = KT + 1;
    __shared__ float Xs[TR][KPAD];
    __shared__ float Wsh[KT][F];
    const int rowBase = blockIdx.x * TR;
    const int tc = threadIdx.x % CT;
    const int tr = threadIdx.x / CT;

    float acc[RPT][4];
    #pragma unroll
    for (int i = 0; i < RPT; ++i)
        #pragma unroll
        for (int j = 0; j < 4; ++j) acc[i][j] = 0.0f;

    for (int k0 = 0; k0 < K; k0 += KT) {
        constexpr int XL4 = TR * KT / 4;
        for (int l = threadIdx.x; l < XL4; l += BLOCK) {
            int r  = l / (KT / 4);
            int kk = (l % (KT / 4)) * 4;
            float4 v = make_float4(0.f, 0.f, 0.f, 0.f);
            int gr = rowBase + r;
            if (gr < NN) v = *reinterpret_cast<const float4*>(X + (size_t)gr * K + k0 + kk);
            Xs[r][kk + 0] = v.x; Xs[r][kk + 1] = v.y;
            Xs[r][kk + 2] = v.z; Xs[r][kk + 3] = v.w;
        }
        constexpr int WL4 = KT * F / 4;
        for (int l = threadIdx.x; l < WL4; l += BLOCK) {
            int kk = l / (F / 4);
            int c  = (l % (F / 4)) * 4;
            *reinterpret_cast<float4*>(&Wsh[kk][c]) =
                *reinterpret_cast<const float4*>(W + (size_t)(k0 + kk) * F + c);
        }
        __syncthreads();
        #pragma unroll
        for (int kk = 0; kk < KT; ++kk) {
            float wv[4];
            *reinterpret_cast<float4*>(wv) = *reinterpret_cast<const float4*>(&Wsh[kk][tc * 4]);
            #pragma unroll
            for (int i = 0; i < RPT; ++i) {
                float a = Xs[tr * RPT + i][kk];
                acc[i][0] = fmaf(a, wv[0], acc[i][0]);
                acc[i][1] = fmaf(a, wv[1], acc[i][1]);
                acc[i][2] = fmaf(a, wv[2], acc[i][2]);
                acc[i][3] = fmaf(a, wv[3], acc[i][3]);
            }
        }
        __syncthreads();
    }
    #pragma unroll
    for (int i = 0; i < RPT; ++i) {
        int gr = rowBase + tr * RPT + i;
        if (gr < NN) {
            float sc = SCALE ? dinv[gr] : 1.0f;
            float4 v;
            v.x = acc[i][0]; v.y = acc[i][1]; v.z = acc[i][2]; v.w = acc[i][3];
            if (BIAS) {
                v.x += b[tc * 4 + 0]; v.y += b[tc * 4 + 1];
                v.z += b[tc * 4 + 2]; v.w += b[tc * 4 + 3];
            }
            v.x *= sc; v.y *= sc; v.z *= sc; v.w *= sc;
            if (OBF16) {
                ushort4 o;
                o.x = f2bf(v.x); o.y = f2bf(v.y); o.z = f2bf(v.z); o.w = f2bf(v.w);
                *reinterpret_cast<ushort4*>((unsigned short*)Yv + (size_t)gr * F + tc * 4) = o;
            } else {
                *reinterpret_cast<float4*>((float*)Yv + (size_t)gr * F + tc * 4) = v;
            }
        }
    }
}

// ---------------- pull (bf16 in, bf16 out): out[d] = dinv_d^2 * (in[d] + sum in[s]) --------
template<int F>
__global__ __launch_bounds__(256)
void pull4bf_k(const unsigned short* __restrict__ in, const int* __restrict__ csr,
               const int* __restrict__ cursor, const float* __restrict__ dinv,
               unsigned short* __restrict__ out) {
    constexpr int LPN = F / 4;
    constexpr int NPB = 256 / LPN;
    const int t = threadIdx.x;
    const int node = blockIdx.x * NPB + t / LPN;
    const int col  = (t % LPN) * 4;
    if (node >= NN) return;
    const int beg = (node == 0) ? 0 : cursor[node - 1];
    const int end = cursor[node];
    float4 a0 = bf4_to_f4(*reinterpret_cast<const ushort4*>(in + (size_t)node * F + col));  // self
    float4 a1 = make_float4(0.f, 0.f, 0.f, 0.f);
    float4 a2 = make_float4(0.f, 0.f, 0.f, 0.f);
    float4 a3 = make_float4(0.f, 0.f, 0.f, 0.f);
    int k = beg;
    for (; k + 3 < end; k += 4) {
        int s0 = csr[k], s1 = csr[k + 1], s2 = csr[k + 2], s3 = csr[k + 3];
        ushort4 h0 = *reinterpret_cast<const ushort4*>(in + (size_t)s0 * F + col);
        ushort4 h1 = *reinterpret_cast<const ushort4*>(in + (size_t)s1 * F + col);
        ushort4 h2 = *reinterpret_cast<const ushort4*>(in + (size_t)s2 * F + col);
        ushort4 h3 = *reinterpret_cast<const ushort4*>(in + (size_t)s3 * F + col);
        float4 v0 = bf4_to_f4(h0), v1 = bf4_to_f4(h1), v2 = bf4_to_f4(h2), v3 = bf4_to_f4(h3);
        a0.x += v0.x; a0.y += v0.y; a0.z += v0.z; a0.w += v0.w;
        a1.x += v1.x; a1.y += v1.y; a1.z += v1.z; a1.w += v1.w;
        a2.x += v2.x; a2.y += v2.y; a2.z += v2.z; a2.w += v2.w;
        a3.x += v3.x; a3.y += v3.y; a3.z += v3.z; a3.w += v3.w;
    }
    for (; k < end; ++k) {
        int s0 = csr[k];
        float4 v0 = bf4_to_f4(*reinterpret_cast<const ushort4*>(in + (size_t)s0 * F + col));
        a0.x += v0.x; a0.y += v0.y; a0.z += v0.z; a0.w += v0.w;
    }
    float sc = dinv[node]; sc *= sc;
    ushort4 o;
    o.x = f2bf((a0.x + a1.x + a2.x + a3.x) * sc);
    o.y = f2bf((a0.y + a1.y + a2.y + a3.y) * sc);
    o.z = f2bf((a0.z + a1.z + a2.z + a3.z) * sc);
    o.w = f2bf((a0.w + a1.w + a2.w + a3.w) * sc);
    *reinterpret_cast<ushort4*>(out + (size_t)node * F + col) = o;
}

// ---------------- fused: hop-2 pull bf16 (+relu) + GEMM W2 + dinv scale -> bf16 t2 ---------
// h = relu(dinv_d*(v[d]+sum v[s]) + b1);  t2[d] = dinv_d * (h @ W2)   [64 -> 32]
__global__ __launch_bounds__(256)
void pullgemm2_k(const unsigned short* __restrict__ in, const int* __restrict__ csr,
                 const int* __restrict__ cursor, const float* __restrict__ dinv,
                 const float* __restrict__ b1, const float* __restrict__ W2,
                 unsigned short* __restrict__ outT) {
    __shared__ float hs[32][68];
    __shared__ float W2s[64][32];
    const int t = threadIdx.x;
    for (int i = t; i < 64 * 32 / 4; i += 256)
        reinterpret_cast<float4*>(&W2s[0][0])[i] = reinterpret_cast<const float4*>(W2)[i];
    const int nodeBase = blockIdx.x * 32;
    #pragma unroll
    for (int pass = 0; pass < 2; ++pass) {
        const int nb = pass * 16 + t / 16;
        const int node = nodeBase + nb;
        const int col = (t % 16) * 4;
        float4 r = make_float4(0.f, 0.f, 0.f, 0.f);
        if (node < NN) {
            const int beg = (node == 0) ? 0 : cursor[node - 1];
            const int end = cursor[node];
            float4 a0 = bf4_to_f4(*reinterpret_cast<const ushort4*>(in + (size_t)node * 64 + col));
            float4 a1 = make_float4(0.f, 0.f, 0.f, 0.f);
            float4 a2 = make_float4(0.f, 0.f, 0.f, 0.f);
            float4 a3 = make_float4(0.f, 0.f, 0.f, 0.f);
            int k = beg;
            for (; k + 3 < end; k += 4) {
                int s0 = csr[k], s1 = csr[k + 1], s2 = csr[k + 2], s3 = csr[k + 3];
                ushort4 h0 = *reinterpret_cast<const ushort4*>(in + (size_t)s0 * 64 + col);
                ushort4 h1 = *reinterpret_cast<const ushort4*>(in + (size_t)s1 * 64 + col);
                ushort4 h2 = *reinterpret_cast<const ushort4*>(in + (size_t)s2 * 64 + col);
                ushort4 h3 = *reinterpret_cast<const ushort4*>(in + (size_t)s3 * 64 + col);
                float4 v0 = bf4_to_f4(h0), v1 = bf4_to_f4(h1);
                float4 v2 = bf4_to_f4(h2), v3 = bf4_to_f4(h3);
                a0.x += v0.x; a0.y += v0.y; a0.z += v0.z; a0.w += v0.w;
                a1.x += v1.x; a1.y += v1.y; a1.z += v1.z; a1.w += v1.w;
                a2.x += v2.x; a2.y += v2.y; a2.z += v2.z; a2.w += v2.w;
                a3.x += v3.x; a3.y += v3.y; a3.z += v3.z; a3.w += v3.w;
            }
            for (; k < end; ++k) {
                int s0 = csr[k];
                float4 v0 = bf4_to_f4(*reinterpret_cast<const ushort4*>(in + (size_t)s0 * 64 + col));
                a0.x += v0.x; a0.y += v0.y; a0.z += v0.z; a0.w += v0.w;
            }
            const float sc = dinv[node];
            const float4 bv = *reinterpret_cast<const float4*>(b1 + col);
            r.x = fmaxf((a0.x + a1.x + a2.x + a3.x) * sc + bv.x, 0.f);
            r.y = fmaxf((a0.y + a1.y + a2.y + a3.y) * sc + bv.y, 0.f);
            r.z = fmaxf((a0.z + a1.z + a2.z + a3.z) * sc + bv.z, 0.f);
            r.w = fmaxf((a0.w + a1.w + a2.w + a3.w) * sc + bv.w, 0.f);
        }
        *reinterpret_cast<float4*>(&hs[nb][col]) = r;
    }
    __syncthreads();
    // GEMM: 32 rows x 32 cols, thread owns (row, 4 cols)
    const int r = t / 8;
    const int c0 = (t % 8) * 4;
    float acc[4] = {0.f, 0.f, 0.f, 0.f};
    #pragma unroll 4
    for (int k = 0; k < 64; k += 4) {
        float4 av = *reinterpret_cast<const float4*>(&hs[r][k]);
        #pragma unroll
        for (int kk = 0; kk < 4; ++kk) {
            float a = (&av.x)[kk];
            float4 w = *reinterpret_cast<const float4*>(&W2s[k + kk][c0]);
            acc[0] = fmaf(a, w.x, acc[0]); acc[1] = fmaf(a, w.y, acc[1]);
            acc[2] = fmaf(a, w.z, acc[2]); acc[3] = fmaf(a, w.w, acc[3]);
        }
    }
    const int node = nodeBase + r;
    if (node < NN) {
        const float sc = dinv[node];
        ushort4 o;
        o.x = f2bf(acc[0] * sc); o.y = f2bf(acc[1] * sc);
        o.z = f2bf(acc[2] * sc); o.w = f2bf(acc[3] * sc);
        *reinterpret_cast<ushort4*>(outT + (size_t)node * 32 + c0) = o;
    }
}

// ---------------- fused: hop-4 pull bf16 (+relu) -> emb, + final GEMM Wf -> logits ---------
__global__ __launch_bounds__(256)
void pullgemmF_k(const unsigned short* __restrict__ in, const int* __restrict__ csr,
                 const int* __restrict__ cursor, const float* __restrict__ dinv,
                 const float* __restrict__ b2, const float* __restrict__ Wf,
                 const float* __restrict__ bf, float* __restrict__ embOut,
                 float* __restrict__ logits) {
    __shared__ float es[32][36];
    __shared__ float Wfs[32][40];
    __shared__ float bfs[40];
    const int t = threadIdx.x;
    for (int i = t; i < 32 * 40 / 4; i += 256)
        reinterpret_cast<float4*>(&Wfs[0][0])[i] = reinterpret_cast<const float4*>(Wf)[i];
    if (t < 40) bfs[t] = bf[t];
    const int nodeBase = blockIdx.x * 32;
    // pull phase: 8 lanes/node, 32 nodes, single pass
    {
        const int nb = t / 8;
        const int node = nodeBase + nb;
        const int col = (t % 8) * 4;
        float4 r = make_float4(0.f, 0.f, 0.f, 0.f);
        if (node < NN) {
            const int beg = (node == 0) ? 0 : cursor[node - 1];
            const int end = cursor[node];
            float4 a0 = bf4_to_f4(*reinterpret_cast<const ushort4*>(in + (size_t)node * 32 + col));
            float4 a1 = make_float4(0.f, 0.f, 0.f, 0.f);
            float4 a2 = make_float4(0.f, 0.f, 0.f, 0.f);
            float4 a3 = make_float4(0.f, 0.f, 0.f, 0.f);
            int k = beg;
            for (; k + 3 < end; k += 4) {
                int s0 = csr[k], s1 = csr[k + 1], s2 = csr[k + 2], s3 = csr[k + 3];
                ushort4 h0 = *reinterpret_cast<const ushort4*>(in + (size_t)s0 * 32 + col);
                ushort4 h1 = *reinterpret_cast<const ushort4*>(in + (size_t)s1 * 32 + col);
                ushort4 h2 = *reinterpret_cast<const ushort4*>(in + (size_t)s2 * 32 + col);
                ushort4 h3 = *reinterpret_cast<const ushort4*>(in + (size_t)s3 * 32 + col);
                float4 v0 = bf4_to_f4(h0), v1 = bf4_to_f4(h1);
                float4 v2 = bf4_to_f4(h2), v3 = bf4_to_f4(h3);
                a0.x += v0.x; a0.y += v0.y; a0.z += v0.z; a0.w += v0.w;
                a1.x += v1.x; a1.y += v1.y; a1.z += v1.z; a1.w += v1.w;
                a2.x += v2.x; a2.y += v2.y; a2.z += v2.z; a2.w += v2.w;
                a3.x += v3.x; a3.y += v3.y; a3.z += v3.z; a3.w += v3.w;
            }
            for (; k < end; ++k) {
                int s0 = csr[k];
                float4 v0 = bf4_to_f4(*reinterpret_cast<const ushort4*>(in + (size_t)s0 * 32 + col));
                a0.x += v0.x; a0.y += v0.y; a0.z += v0.z; a0.w += v0.w;
            }
            const float sc = dinv[node];
            const float4 bv = *reinterpret_cast<const float4*>(b2 + col);
            r.x = fmaxf((a0.x + a1.x + a2.x + a3.x) * sc + bv.x, 0.f);
            r.y = fmaxf((a0.y + a1.y + a2.y + a3.y) * sc + bv.y, 0.f);
            r.z = fmaxf((a0.z + a1.z + a2.z + a3.z) * sc + bv.z, 0.f);
            r.w = fmaxf((a0.w + a1.w + a2.w + a3.w) * sc + bv.w, 0.f);
            *reinterpret_cast<float4*>(embOut + (size_t)node * 32 + col) = r;
        }
        *reinterpret_cast<float4*>(&es[nb][col]) = r;
    }
    __syncthreads();
    // GEMM: 32 rows x 40 cols, thread owns (row, 5 cols)
    const int r = t / 8;
    const int c0 = (t % 8) * 5;
    float acc[5];
    #pragma unroll
    for (int j = 0; j < 5; ++j) acc[j] = bfs[c0 + j];
    #pragma unroll 4
    for (int k = 0; k < 32; k += 4) {
        float4 av = *reinterpret_cast<const float4*>(&es[r][k]);
        #pragma unroll
        for (int kk = 0; kk < 4; ++kk) {
            float a = (&av.x)[kk];
            #pragma unroll
            for (int j = 0; j < 5; ++j)
                acc[j] = fmaf(a, Wfs[k + kk][c0 + j], acc[j]);
        }
    }
    const int node = nodeBase + r;
    if (node < NN) {
        float* lp = logits + (size_t)node * 40 + c0;
        #pragma unroll
        for (int j = 0; j < 5; ++j) lp[j] = acc[j];
    }
}

extern "C" void kernel_launch(void* const* d_in, const int* in_sizes, int n_in,
                              void* d_out, int out_size, void* d_ws, size_t ws_size,
                              hipStream_t stream) {
    const float* x  = (const float*)d_in[0];
    const int*   ei = (const int*)d_in[1];
    const float* W1 = (const float*)d_in[2];
    const float* b1 = (const float*)d_in[3];
    const float* W2 = (const float*)d_in[4];
    const float* b2 = (const float*)d_in[5];
    const float* Wf = (const float*)d_in[6];
    const float* bf = (const float*)d_in[7];

    float* out    = (float*)d_out;
    float* embOut = out;                       // [N, 32]
    float* logits = out + (size_t)NN * H2_F;   // [N, 40]

    const int* src = ei;        // edge_index[0]
    const int* dst = ei + NE;   // edge_index[1]

    // workspace layout (16B-aligned blocks)
    float* ws       = (float*)d_ws;
    float* dinv     = ws;                           // NN f32
    int*   cursor   = (int*)(ws + NN);              // NN i32
    int*   csr      = cursor + NN;                  // NE i32
    int*   gCursor  = csr + NE;                     // 512 i32
    int*   segBase  = gCursor + 512;                // 512 i32
    float* bufA     = (float*)(segBase + 512);      // NN*64 f32 region
    float* bufB     = bufA + (size_t)NN * 64;       // NN*64 f32 region
    uint2* pairs    = (uint2*)bufB;                 // 12.6MB, dead before pull #1 writes bufB
    unsigned short* tbf  = (unsigned short*)bufA;   // t  [NN,64] bf16 (6.4MB)
    unsigned short* t2bf = (unsigned short*)bufA;   // t2 [NN,32] bf16 (reuses after t dead)
    unsigned short* vbf  = (unsigned short*)bufB;   // v  [NN,64] bf16 (6.4MB)
    unsigned short* ubf  = (unsigned short*)bufB;   // u  [NN,32] bf16 (reuses after v dead)

    // ---- CSR build + dinv (bucketized, XCD-local writes) ----
    initcur_k<<<cdiv(NBKT, 256), 256, 0, stream>>>(gCursor);
    binA_k<<<NCH, 256, 0, stream>>>(src, dst, pairs, gCursor);
    segscan_k<<<1, 512, 0, stream>>>(gCursor, segBase);
    binB_k<<<NBKT, 256, 0, stream>>>(pairs, gCursor, segBase, cursor, dinv, csr);

    // ---- layer 1 ----
    gemm_tile_k<IN_F, H1_F, 16, 4, 256, false, true, true>
        <<<cdiv(NN, 64), 256, 0, stream>>>(x, W1, nullptr, dinv, tbf);           // t -> bf16
    pull4bf_k<H1_F>
        <<<cdiv(NN, 256 / (H1_F / 4)), 256, 0, stream>>>(tbf, csr, cursor, dinv, vbf);    // v -> bf16
    pullgemm2_k
        <<<cdiv(NN, 32), 256, 0, stream>>>(vbf, csr, cursor, dinv, b1, W2, t2bf);         // t2 -> bf16

    // ---- layer 2 ----
    pull4bf_k<H2_F>
        <<<cdiv(NN, 256 / (H2_F / 4)), 256, 0, stream>>>(t2bf, csr, cursor, dinv, ubf);   // u -> bf16
    pullgemmF_k
        <<<cdiv(NN, 32), 256, 0, stream>>>(ubf, csr, cursor, dinv, b2, Wf, bf, embOut, logits);
}